// Round 9
// baseline (1381.961 us; speedup 1.0000x reference)
//
#include <hip/hip_runtime.h>

#define NN 20000
#define NE 200000
#define NG 512

__device__ __forceinline__ int lowerb(const int* a, int n, int v){
  int lo=0, hi=n;
  while(lo<hi){ int m=(lo+hi)>>1; if(a[m]<v) lo=m+1; else hi=m; }
  return lo;
}

// ---------------- counting sort by tgt -> CSR ----------------
__global__ void k_count(const int* __restrict__ tgt, int* __restrict__ cnt){
  int e = blockIdx.x*blockDim.x + threadIdx.x;
  if(e<NE) atomicAdd(&cnt[tgt[e]], 1);
}

__global__ void k_scan(const int* __restrict__ cnt, int* __restrict__ row_start){
  __shared__ int part[1024];
  int t = threadIdx.x;
  const int CH = (NN + 1023)/1024; // 20
  int i0 = t*CH;
  int s = 0;
  for(int j=0;j<CH;j++){ int i=i0+j; if(i<NN) s += cnt[i]; }
  part[t] = s; __syncthreads();
  for(int d=1; d<1024; d<<=1){
    int v = (t>=d) ? part[t-d] : 0;
    __syncthreads();
    part[t] += v;
    __syncthreads();
  }
  int run = (t==0) ? 0 : part[t-1];
  for(int j=0;j<CH;j++){ int i=i0+j; if(i<NN){ row_start[i]=run; run += cnt[i]; } }
  if(t==0) row_start[NN] = part[1023];
}

// place edges in CSR order AND gather edge_attr to CSR order (fused)
__global__ void k_place(const int* __restrict__ src, const int* __restrict__ tgt,
                        const float* __restrict__ ea,
                        const int* __restrict__ row_start, int* __restrict__ cur,
                        int* __restrict__ es_src, float* __restrict__ es_ea){
  int e = blockIdx.x*blockDim.x + threadIdx.x;
  if(e>=NE) return;
  int n = tgt[e];
  int pos = row_start[n] + atomicAdd(&cur[n],1);
  es_src[pos] = src[e];
  const float4* s = (const float4*)ea + (size_t)e*4;
  float4* d = (float4*)es_ea + (size_t)pos*4;
  d[0]=s[0]; d[1]=s[1]; d[2]=s[2]; d[3]=s[3];
}

// ---------------- H = relu(es_ea @ W1 + b1), CSR-ordered, E x 128 ----------------
__launch_bounds__(256, 4)
__global__ void k_hmlp(const float* __restrict__ es_ea, const float* __restrict__ W1,
                       const float* __restrict__ b1, float* __restrict__ H){
  const int pc = threadIdx.x & 31, er = threadIdx.x >> 5;
  const size_t e = (size_t)blockIdx.x*8 + er;
  float4 w1v[16];
  #pragma unroll
  for(int i=0;i<16;i++) w1v[i] = *(const float4*)&W1[i*128 + pc*4];
  float4 hv = *(const float4*)&b1[pc*4];
  float eav[16];
  const float4* eap = (const float4*)(es_ea + e*16);
  #pragma unroll
  for(int q=0;q<4;q++){
    float4 v = eap[q];
    eav[q*4+0]=v.x; eav[q*4+1]=v.y; eav[q*4+2]=v.z; eav[q*4+3]=v.w;
  }
  #pragma unroll
  for(int i=0;i<16;i++){
    hv.x += eav[i]*w1v[i].x;
    hv.y += eav[i]*w1v[i].y;
    hv.z += eav[i]*w1v[i].z;
    hv.w += eav[i]*w1v[i].w;
  }
  hv.x = fmaxf(hv.x,0.f); hv.y = fmaxf(hv.y,0.f);
  hv.z = fmaxf(hv.z,0.f); hv.w = fmaxf(hv.w,0.f);
  *(float4*)&H[e*128 + pc*4] = hv;
}

// ---------------- xbar[n,i] = mean over in-edges of x[src,i] (L2 only) ----------------
template<int IC>
__global__ void k_xbar(const float* __restrict__ x, const int* __restrict__ es_src,
                       const int* __restrict__ row_start, float* __restrict__ xbar){
  constexpr int TI = IC/16;
  const int wid = threadIdx.x>>6, lane = threadIdx.x&63;
  const int n = blockIdx.x*4 + wid;
  const int eg = lane>>4, ig = lane&15;
  const int a = row_start[n], b = row_start[n+1];
  float s[TI];
  #pragma unroll
  for(int u=0;u<TI;u++) s[u]=0.f;
  for(int e=a+eg; e<b; e+=4){
    int sn = es_src[e];
    #pragma unroll
    for(int u=0;u<TI;u++) s[u] += x[(size_t)sn*IC + ig*TI + u];
  }
  #pragma unroll
  for(int u=0;u<TI;u++){
    s[u] += __shfl_xor(s[u], 16, 64);
    s[u] += __shfl_xor(s[u], 32, 64);
  }
  if(eg==0){
    float dinv = 1.f/fmaxf((float)(b-a), 1.f);
    #pragma unroll
    for(int u=0;u<TI;u++) xbar[(size_t)n*IC + ig*TI + u] = s[u]*dinv;
  }
}

// ---------------- fused NNConv layer: R5 tiles + dbuf staging + pipelined GEMM ----------------
// Thread tile (scatter): pw = tid/NPW owns PP p-values, iw = tid%NPW owns TI i-values.
// acc[BN][PP][TI] <= 48 floats (spill rule). Double-buffered staging: global->reg loads
// for batch b+1 issue before scatter(b); reg->LDS writes after the scatter barrier.
// XB: fuse xbar (mean of x over in-edges) into scatter/dump (pw==0 threads).
template<int IC, int OC, int PLEN, int KS, int BN, int PP, int TI, int KQ, int TO,
         int EBT, bool XB>
__launch_bounds__(256, 3)
__global__ void k_layer(const float* __restrict__ x_in, const float* __restrict__ H,
                        const int* __restrict__ es_src, const int* __restrict__ row_start,
                        const float* __restrict__ W2, float* __restrict__ part,
                        float* __restrict__ xbar)
{
  constexpr int K   = PLEN*IC;
  constexpr int HV4 = PLEN/4;
  constexpr int XV  = IC/4;
  constexpr int NPW = IC/TI;
  constexpr int ACT = (PLEN/PP)*NPW;
  constexpr int J   = K/4/KQ;
  constexpr int STG = EBT*(PLEN+IC);
  constexpr int NH4 = (EBT*HV4 + 255)/256;
  constexpr int NX4 = (EBT*XV  + 255)/256;
  static_assert(BN*PP*TI <= 48, "spill-safe accumulator");
  static_assert(2*STG <= BN*K, "double-buffered staging aliases into S");
  static_assert((256/KQ)*TO==OC && (K/4)%KQ==0 && ACT<=256, "tiling");

  __shared__ __align__(16) float S[BN*K];
  __shared__ int rs_s[BN+1];
  __shared__ int ro2[2][BN+1];

  const int tid = threadIdx.x;
  const int split = blockIdx.x % KS;
  const int nb = blockIdx.x / KS;
  const int n0 = nb*BN;
  const int p04 = split*HV4;

  if(tid<=BN) rs_s[tid] = row_start[n0+tid];
  __syncthreads();
  const int estart = rs_s[0], eend = rs_s[BN];
  const int nbatch = (eend - estart + EBT - 1)/EBT;

  const int pw = tid / NPW;
  const int iw = tid - pw*NPW;

  float acc[BN][PP][TI];
  #pragma unroll
  for(int n=0;n<BN;n++)
    #pragma unroll
    for(int p=0;p<PP;p++)
      #pragma unroll
      for(int u=0;u<TI;u++) acc[n][p][u]=0.f;
  float xsum[BN][TI];
  if constexpr (XB){
    #pragma unroll
    for(int n=0;n<BN;n++)
      #pragma unroll
      for(int u=0;u<TI;u++) xsum[n][u]=0.f;
  }

  const float4* H4 = (const float4*)H;
  const float4* x4 = (const float4*)x_in;

  float4 rh[NH4], rx[NX4];
  auto load_batch = [&](int b){
    const int bstart = estart + b*EBT;
    const int ebc = min(EBT, eend-bstart);
    #pragma unroll
    for(int t=0;t<NH4;t++){
      int j = tid + t*256;
      if(j < ebc*HV4){ int e = j/HV4, q = j - e*HV4;
        rh[t] = H4[(size_t)(bstart+e)*32 + p04 + q]; }
    }
    #pragma unroll
    for(int t=0;t<NX4;t++){
      int j = tid + t*256;
      if(j < ebc*XV){ int e = j/XV, q = j - e*XV;
        rx[t] = x4[(size_t)es_src[bstart+e]*XV + q]; }
    }
    if(tid<=BN){ int v = rs_s[tid]-bstart; ro2[b&1][tid] = min(max(v,0), ebc); }
  };
  auto write_batch = [&](int b){
    const int bstart = estart + b*EBT;
    const int ebc = min(EBT, eend-bstart);
    float* hb = S + (b&1)*STG;
    float* xs = hb + EBT*PLEN;
    #pragma unroll
    for(int t=0;t<NH4;t++){ int j = tid + t*256; if(j < ebc*HV4) ((float4*)hb)[j] = rh[t]; }
    #pragma unroll
    for(int t=0;t<NX4;t++){ int j = tid + t*256; if(j < ebc*XV)  ((float4*)xs)[j] = rx[t]; }
  };

  if(nbatch>0){ load_batch(0); write_batch(0); }
  __syncthreads();

  for(int b=0;b<nbatch;b++){
    if(b+1<nbatch) load_batch(b+1);        // VMEM in flight during scatter
    const float* hb = S + (b&1)*STG;
    const float* xs = hb + EBT*PLEN;
    const int* ro = ro2[b&1];
    if(tid < ACT){
      #pragma unroll
      for(int nl=0; nl<BN; nl++){
        const int a = ro[nl], bb = ro[nl+1];
        for(int e=a; e<bb; e++){
          float hv[PP];
          if constexpr (PP==4){
            float4 h = *(const float4*)&hb[e*PLEN + pw*4];
            hv[0]=h.x; hv[1]=h.y; hv[2]=h.z; hv[3]=h.w;
          } else if constexpr (PP==2){
            float2 h = *(const float2*)&hb[e*PLEN + pw*2];
            hv[0]=h.x; hv[1]=h.y;
          } else {
            hv[0]=hb[e*PLEN + pw];
          }
          float xv[TI];
          if constexpr (TI==4){
            float4 xq = *(const float4*)&xs[e*IC + iw*4];
            xv[0]=xq.x; xv[1]=xq.y; xv[2]=xq.z; xv[3]=xq.w;
          } else if constexpr (TI==2){
            float2 xq = *(const float2*)&xs[e*IC + iw*2];
            xv[0]=xq.x; xv[1]=xq.y;
          } else {
            #pragma unroll
            for(int u=0;u<TI;u++) xv[u] = xs[e*IC + iw*TI + u];
          }
          #pragma unroll
          for(int p=0;p<PP;p++)
            #pragma unroll
            for(int u=0;u<TI;u++) acc[nl][p][u] += hv[p]*xv[u];
          if constexpr (XB){
            if(pw==0){
              #pragma unroll
              for(int u=0;u<TI;u++) xsum[nl][u] += xv[u];
            }
          }
        }
      }
    }
    __syncthreads();                        // all waves done with buffer b
    if(b+1<nbatch){ write_batch(b+1); __syncthreads(); }
  }

  // dump scaled S (staging area dead)
  if(tid < ACT){
    #pragma unroll
    for(int n=0;n<BN;n++){
      const float dv = 1.f/fmaxf((float)(rs_s[n+1]-rs_s[n]), 1.f);
      #pragma unroll
      for(int p=0;p<PP;p++)
        #pragma unroll
        for(int u=0;u<TI;u++)
          S[(n*PLEN + pw*PP + p)*IC + iw*TI + u] = acc[n][p][u]*dv;
      if constexpr (XB){
        if(pw==0){
          #pragma unroll
          for(int u=0;u<TI;u++) xbar[(size_t)(n0+n)*IC + iw*TI + u] = xsum[n][u]*dv;
        }
      }
    }
  }
  __syncthreads();

  // ---- GEMM: part[split][n][o] = sum_k S[n][k] * W2[split*K + k][o] (pipelined W2) ----
  const int kq = tid % KQ, oq = tid / KQ;
  const int o0 = oq*TO;
  const float* W2b = W2 + (size_t)split*K*OC + o0;
  float outp[BN][TO];
  #pragma unroll
  for(int n=0;n<BN;n++)
    #pragma unroll
    for(int t=0;t<TO;t++) outp[n][t]=0.f;

  float wv[2][4][TO];
  auto loadW = [&](int j, int s){
    const int k4 = j*KQ + kq;
    #pragma unroll
    for(int r=0;r<4;r++){
      const float* wr = W2b + (size_t)(4*k4+r)*OC;
      if constexpr (TO==4){
        float4 a=*(const float4*)wr;
        wv[s][r][0]=a.x; wv[s][r][1]=a.y; wv[s][r][2]=a.z; wv[s][r][3]=a.w;
      } else if constexpr (TO==3){
        wv[s][r][0]=wr[0]; wv[s][r][1]=wr[1]; wv[s][r][2]=wr[2];
      } else {
        float2 a=*(const float2*)wr;
        wv[s][r][0]=a.x; wv[s][r][1]=a.y;
      }
    }
  };
  loadW(0,0);
  for(int j=0;j<J;j++){
    if(j+1<J) loadW(j+1,(j+1)&1);
    const int k4 = j*KQ + kq;
    const int s = j&1;
    #pragma unroll
    for(int n=0;n<BN;n++){
      float4 sv = *(const float4*)&S[n*K + 4*k4];
      #pragma unroll
      for(int t=0;t<TO;t++)
        outp[n][t] += sv.x*wv[s][0][t] + sv.y*wv[s][1][t] + sv.z*wv[s][2][t] + sv.w*wv[s][3][t];
    }
  }
  // reduce over KQ lanes
  #pragma unroll
  for(int m=KQ>>1; m>=1; m>>=1)
    #pragma unroll
    for(int n=0;n<BN;n++)
      #pragma unroll
      for(int t=0;t<TO;t++) outp[n][t] += __shfl_xor(outp[n][t], m, 64);

  if(kq==0){
    #pragma unroll
    for(int n=0;n<BN;n++){
      float* dst = part + ((size_t)split*NN + n0+n)*OC + o0;
      #pragma unroll
      for(int t=0;t<TO;t++) dst[t] = outp[n][t];
    }
  }
}

// ---------------- epilogue: y = relu(sum_s part[s] + x@root + xbar@b2 + bias) ----------------
template<int IC, int OC, int KS>
__global__ void k_epi(const float* __restrict__ part, const float* __restrict__ x,
                      const float* __restrict__ xbar,
                      const float* __restrict__ root, const float* __restrict__ b2,
                      const float* __restrict__ bias, float* __restrict__ y)
{
  int idx = blockIdx.x*256 + threadIdx.x;
  if(idx >= NN*OC) return;
  int n = idx/OC, o = idx - n*OC;
  float v = bias[o];
  #pragma unroll
  for(int s=0;s<KS;s++) v += part[(size_t)s*NN*OC + idx];
  #pragma unroll
  for(int i=0;i<IC;i++) v += x[(size_t)n*IC+i]*root[i*OC+o];
  #pragma unroll
  for(int i=0;i<IC;i++) v += xbar[(size_t)n*IC+i]*b2[i*OC+o];
  y[idx] = fmaxf(v, 0.f);
}

// ---------------- set2set (2 steps) + final MLP, one wave per graph ----------------
__global__ void k_s2s(const float* __restrict__ xg, const int* __restrict__ batch,
  const float* __restrict__ Wih, const float* __restrict__ Whh,
  const float* __restrict__ bih, const float* __restrict__ bhh,
  const float* __restrict__ l1W, const float* __restrict__ l1b,
  const float* __restrict__ l2W, const float* __restrict__ l2b,
  const float* __restrict__ lfW, const float* __restrict__ lfb,
  float* __restrict__ out)
{
  int g = blockIdx.x, lane = threadIdx.x;
  __shared__ float hs[16], cs[16], qs[32], gs[64], rs[16];
  int r0 = lowerb(batch, NN, g);
  int r1 = lowerb(batch, NN, g+1);
  if(lane<16){ hs[lane]=0.f; cs[lane]=0.f; }
  if(lane<32) qs[lane]=0.f;
  __syncthreads();
  for(int step=0; step<2; step++){
    float gate = bih[lane] + bhh[lane];
    for(int k=0;k<32;k++) gate += qs[k]*Wih[lane*32+k];
    for(int k=0;k<16;k++) gate += hs[k]*Whh[lane*16+k];
    gs[lane] = gate;
    __syncthreads();
    if(lane<16){
      float ig = 1.f/(1.f+expf(-gs[lane]));
      float fg = 1.f/(1.f+expf(-gs[lane+16]));
      float gg = tanhf(gs[lane+32]);
      float og = 1.f/(1.f+expf(-gs[lane+48]));
      float cn = fg*cs[lane] + ig*gg;
      cs[lane] = cn;
      hs[lane] = og*tanhf(cn);
    }
    __syncthreads();
    float m = -1e30f;
    for(int n=r0+lane; n<r1; n+=64){
      float e=0.f;
      for(int k=0;k<16;k++) e += xg[n*16+k]*hs[k];
      m = fmaxf(m, e);
    }
    for(int d=1; d<64; d<<=1) m = fmaxf(m, __shfl_xor(m, d));
    float ssum = 0.f;
    float racc[16];
    #pragma unroll
    for(int k=0;k<16;k++) racc[k]=0.f;
    for(int n=r0+lane; n<r1; n+=64){
      float e=0.f, xv[16];
      #pragma unroll
      for(int k=0;k<16;k++){ xv[k]=xg[n*16+k]; e += xv[k]*hs[k]; }
      float a = expf(e - m);
      ssum += a;
      #pragma unroll
      for(int k=0;k<16;k++) racc[k] += a*xv[k];
    }
    for(int d=1; d<64; d<<=1) ssum += __shfl_xor(ssum, d);
    #pragma unroll
    for(int k=0;k<16;k++)
      for(int d=1; d<64; d<<=1) racc[k] += __shfl_xor(racc[k], d);
    ssum = fmaxf(ssum, 1e-16f);
    if(lane==0){
      #pragma unroll
      for(int k=0;k<16;k++) rs[k] = racc[k]/ssum;
    }
    __syncthreads();
    if(lane<16){ qs[lane]=hs[lane]; qs[16+lane]=rs[lane]; }
    __syncthreads();
  }
  if(lane<16){
    float v = l1b[lane];
    for(int k=0;k<32;k++) v += qs[k]*l1W[k*16+lane];
    gs[lane] = fmaxf(v,0.f);
  }
  __syncthreads();
  if(lane<8){
    float v = l2b[lane];
    for(int k=0;k<16;k++) v += gs[k]*l2W[k*8+lane];
    gs[32+lane] = fmaxf(v,0.f);
  }
  __syncthreads();
  if(lane==0){
    float v = lfb[0];
    for(int k=0;k<8;k++) v += gs[32+k]*lfW[k];
    out[g] = v;
  }
}

extern "C" void kernel_launch(void* const* d_in, const int* in_sizes, int n_in,
                              void* d_out, int out_size, void* d_ws, size_t ws_size,
                              hipStream_t stream) {
  const float* x0   = (const float*)d_in[0];
  const int*   ei   = (const int*)d_in[1];
  const float* ea   = (const float*)d_in[2];
  const int*   batch= (const int*)d_in[3];
  const float* c1W1 = (const float*)d_in[4];  const float* c1b1 = (const float*)d_in[5];
  const float* c1W2 = (const float*)d_in[6];  const float* c1b2 = (const float*)d_in[7];
  const float* c1rt = (const float*)d_in[8];  const float* c1bs = (const float*)d_in[9];
  const float* c2W1 = (const float*)d_in[10]; const float* c2b1 = (const float*)d_in[11];
  const float* c2W2 = (const float*)d_in[12]; const float* c2b2 = (const float*)d_in[13];
  const float* c2rt = (const float*)d_in[14]; const float* c2bs = (const float*)d_in[15];
  const float* c3W1 = (const float*)d_in[16]; const float* c3b1 = (const float*)d_in[17];
  const float* c3W2 = (const float*)d_in[18]; const float* c3b2 = (const float*)d_in[19];
  const float* c3rt = (const float*)d_in[20]; const float* c3bs = (const float*)d_in[21];
  const float* Wih  = (const float*)d_in[22]; const float* Whh  = (const float*)d_in[23];
  const float* bih  = (const float*)d_in[24]; const float* bhh  = (const float*)d_in[25];
  const float* l1W  = (const float*)d_in[26]; const float* l1b  = (const float*)d_in[27];
  const float* l2W  = (const float*)d_in[28]; const float* l2b  = (const float*)d_in[29];
  const float* lfW  = (const float*)d_in[30]; const float* lfb  = (const float*)d_in[31];
  float* out = (float*)d_out;

  const int* src = ei;
  const int* tgt = ei + NE;

  // workspace carve (~140 MB)
  char* w = (char*)d_ws;
  auto carve = [&](size_t bytes)->void*{ void* p = (void*)w; w += (bytes + 255) & ~(size_t)255; return p; };
  int*   row_start = (int*)carve((NN+1)*sizeof(int));
  int*   cur       = (int*)carve(NN*sizeof(int));
  int*   es_src    = (int*)carve(NE*sizeof(int));
  float* es_ea     = (float*)carve((size_t)NE*16*sizeof(float));
  float* Hbuf      = (float*)carve((size_t)NE*128*sizeof(float));
  float* xbar      = (float*)carve((size_t)NN*48*sizeof(float));
  float* y1   = (float*)carve((size_t)NN*48*sizeof(float));
  float* y2   = (float*)carve((size_t)NN*32*sizeof(float));
  float* y3   = (float*)carve((size_t)NN*16*sizeof(float));
  float* part = (float*)carve((size_t)4*NN*48*sizeof(float));

  // ---- CSR by tgt (+ fused ea gather)
  hipMemsetAsync(cur, 0, NN*sizeof(int), stream);
  k_count<<<(NE+255)/256, 256, 0, stream>>>(tgt, cur);
  k_scan<<<1, 1024, 0, stream>>>(cur, row_start);
  hipMemsetAsync(cur, 0, NN*sizeof(int), stream);
  k_place<<<(NE+255)/256, 256, 0, stream>>>(src, tgt, ea, row_start, cur, es_src, es_ea);

  // ---- layer 1: IC=16 OC=48 | PLEN=64 KS=2 BN=8 PP=4 TI=1 | KQ=16 TO=3 | EBT=48, xbar fused
  k_hmlp<<<NE/8, 256, 0, stream>>>(es_ea, c1W1, c1b1, Hbuf);
  k_layer<16,48,64,2,8,4,1,16,3,48,true><<<(NN/8)*2, 256, 0, stream>>>(x0, Hbuf, es_src, row_start, c1W2, part, xbar);
  k_epi<16,48,2><<<(NN*48+255)/256, 256, 0, stream>>>(part, x0, xbar, c1rt, c1b2, c1bs, y1);

  // ---- layer 2: IC=48 OC=32 | PLEN=32 KS=4 BN=8 PP=2 TI=3 | KQ=32 TO=4 | EBT=64, k_xbar kernel
  k_hmlp<<<NE/8, 256, 0, stream>>>(es_ea, c2W1, c2b1, Hbuf);
  k_xbar<48><<<NN/4, 256, 0, stream>>>(y1, es_src, row_start, xbar);
  k_layer<48,32,32,4,8,2,3,32,4,64,false><<<(NN/8)*4, 256, 0, stream>>>(y1, Hbuf, es_src, row_start, c2W2, part, xbar);
  k_epi<48,32,4><<<(NN*32+255)/256, 256, 0, stream>>>(part, y1, xbar, c2rt, c2b2, c2bs, y2);

  // ---- layer 3: IC=32 OC=16 | PLEN=64 KS=2 BN=4 PP=4 TI=2 | KQ=32 TO=2 | EBT=40, xbar fused
  k_hmlp<<<NE/8, 256, 0, stream>>>(es_ea, c3W1, c3b1, Hbuf);
  k_layer<32,16,64,2,4,4,2,32,2,40,true><<<(NN/4)*2, 256, 0, stream>>>(y2, Hbuf, es_src, row_start, c3W2, part, xbar);
  k_epi<32,16,2><<<(NN*16+255)/256, 256, 0, stream>>>(part, y2, xbar, c3rt, c3b2, c3bs, y3);

  // ---- set2set + MLP head
  k_s2s<<<NG, 64, 0, stream>>>(y3, batch, Wih, Whh, bih, bhh, l1W, l1b, l2W, l2b, lfW, lfb, out);
}

// Round 10
// 1200.737 us; speedup vs baseline: 1.1509x; 1.1509x over previous
//
#include <hip/hip_runtime.h>

#define NN 20000
#define NE 200000
#define NG 512

constexpr int EB = 64;   // edges staged per batch

__device__ __forceinline__ int lowerb(const int* a, int n, int v){
  int lo=0, hi=n;
  while(lo<hi){ int m=(lo+hi)>>1; if(a[m]<v) lo=m+1; else hi=m; }
  return lo;
}

// ---------------- counting sort by tgt -> CSR ----------------
__global__ void k_count(const int* __restrict__ tgt, int* __restrict__ cnt){
  int e = blockIdx.x*blockDim.x + threadIdx.x;
  if(e<NE) atomicAdd(&cnt[tgt[e]], 1);
}

__global__ void k_scan(const int* __restrict__ cnt, int* __restrict__ row_start){
  __shared__ int part[1024];
  int t = threadIdx.x;
  const int CH = (NN + 1023)/1024; // 20
  int i0 = t*CH;
  int s = 0;
  for(int j=0;j<CH;j++){ int i=i0+j; if(i<NN) s += cnt[i]; }
  part[t] = s; __syncthreads();
  for(int d=1; d<1024; d<<=1){
    int v = (t>=d) ? part[t-d] : 0;
    __syncthreads();
    part[t] += v;
    __syncthreads();
  }
  int run = (t==0) ? 0 : part[t-1];
  for(int j=0;j<CH;j++){ int i=i0+j; if(i<NN){ row_start[i]=run; run += cnt[i]; } }
  if(t==0) row_start[NN] = part[1023];
}

// place edges in CSR order AND gather edge_attr to CSR order (fused)
__global__ void k_place(const int* __restrict__ src, const int* __restrict__ tgt,
                        const float* __restrict__ ea,
                        const int* __restrict__ row_start, int* __restrict__ cur,
                        int* __restrict__ es_src, float* __restrict__ es_ea){
  int e = blockIdx.x*blockDim.x + threadIdx.x;
  if(e>=NE) return;
  int n = tgt[e];
  int pos = row_start[n] + atomicAdd(&cur[n],1);
  es_src[pos] = src[e];
  const float4* s = (const float4*)ea + (size_t)e*4;
  float4* d = (float4*)es_ea + (size_t)pos*4;
  d[0]=s[0]; d[1]=s[1]; d[2]=s[2]; d[3]=s[3];
}

// ---------------- H = relu(es_ea @ W1 + b1), CSR-ordered, E x 128 ----------------
__launch_bounds__(256, 4)
__global__ void k_hmlp(const float* __restrict__ es_ea, const float* __restrict__ W1,
                       const float* __restrict__ b1, float* __restrict__ H){
  const int pc = threadIdx.x & 31, er = threadIdx.x >> 5;
  const size_t e = (size_t)blockIdx.x*8 + er;
  float4 w1v[16];
  #pragma unroll
  for(int i=0;i<16;i++) w1v[i] = *(const float4*)&W1[i*128 + pc*4];
  float4 hv = *(const float4*)&b1[pc*4];
  float eav[16];
  const float4* eap = (const float4*)(es_ea + e*16);
  #pragma unroll
  for(int q=0;q<4;q++){
    float4 v = eap[q];
    eav[q*4+0]=v.x; eav[q*4+1]=v.y; eav[q*4+2]=v.z; eav[q*4+3]=v.w;
  }
  #pragma unroll
  for(int i=0;i<16;i++){
    hv.x += eav[i]*w1v[i].x;
    hv.y += eav[i]*w1v[i].y;
    hv.z += eav[i]*w1v[i].z;
    hv.w += eav[i]*w1v[i].w;
  }
  hv.x = fmaxf(hv.x,0.f); hv.y = fmaxf(hv.y,0.f);
  hv.z = fmaxf(hv.z,0.f); hv.w = fmaxf(hv.w,0.f);
  *(float4*)&H[e*128 + pc*4] = hv;
}

// ---------------- xbar[n,i] = mean over in-edges of x[src,i] ----------------
template<int IC>
__global__ void k_xbar(const float* __restrict__ x, const int* __restrict__ es_src,
                       const int* __restrict__ row_start, float* __restrict__ xbar){
  constexpr int TI = IC/16;
  const int wid = threadIdx.x>>6, lane = threadIdx.x&63;
  const int n = blockIdx.x*4 + wid;
  const int eg = lane>>4, ig = lane&15;
  const int a = row_start[n], b = row_start[n+1];
  float s[TI];
  #pragma unroll
  for(int u=0;u<TI;u++) s[u]=0.f;
  for(int e=a+eg; e<b; e+=4){
    int sn = es_src[e];
    #pragma unroll
    for(int u=0;u<TI;u++) s[u] += x[(size_t)sn*IC + ig*TI + u];
  }
  #pragma unroll
  for(int u=0;u<TI;u++){
    s[u] += __shfl_xor(s[u], 16, 64);
    s[u] += __shfl_xor(s[u], 32, 64);
  }
  if(eg==0){
    float dinv = 1.f/fmaxf((float)(b-a), 1.f);
    #pragma unroll
    for(int u=0;u<TI;u++) xbar[(size_t)n*IC + ig*TI + u] = s[u]*dinv;
  }
}

// ---------------- fused NNConv layer: wave-private register scatter + GEMM ----------------
// Wave w owns G=BN/4 nodes; within a wave, lane = (pw: PLEN/PP groups, iw: IC/TI groups),
// NPW*NIW == 64. acc[G][PP][TI] <= 48 floats (spill rule). Staging cooperative in LDS;
// scatter reads only by the owning wave (LDS-pipe /4 vs all-wave scatter).
// GEMM: kq k-split, oq o-group; reduction = butterfly reduce-scatter when BN*TO==KQ
// (31 shuffles vs 160 tree), else tree.
template<int IC, int OC, int PLEN, int KS, int BN, int PP, int TI, int KQ, int TO, bool RS>
__launch_bounds__(256, 3)
__global__ void k_layer(const float* __restrict__ x_in, const float* __restrict__ H,
                        const int* __restrict__ es_src, const int* __restrict__ row_start,
                        const float* __restrict__ W2, float* __restrict__ part)
{
  constexpr int K   = PLEN*IC;
  constexpr int HV4 = PLEN/4;
  constexpr int XV  = IC/4;
  constexpr int NIW = IC/TI;
  constexpr int NPW = PLEN/PP;
  constexpr int G   = BN/4;
  constexpr int J   = K/4/KQ;
  static_assert(NPW*NIW==64, "wave tile covers 64 lanes");
  static_assert(G*PP*TI <= 48, "spill-safe accumulator");
  static_assert(EB*(PLEN+IC) <= BN*K, "staging alias fits in S");
  static_assert((256/KQ)*TO==OC && (K/4)%KQ==0, "gemm tiling");
  static_assert(!RS || (BN*TO==KQ), "reduce-scatter shape");

  __shared__ __align__(16) float S[BN*K];
  __shared__ int rs_s[BN+1], ro[BN+1];

  float* hb = S;                 // EB*PLEN staged H slice
  float* xs = S + EB*PLEN;       // EB*IC staged x[src]

  const int tid = threadIdx.x;
  const int wid = tid>>6, lane = tid&63;
  const int split = blockIdx.x % KS;
  const int nb = blockIdx.x / KS;
  const int n0 = nb*BN;
  const int p04 = split*HV4;

  if(tid<=BN) rs_s[tid] = row_start[n0+tid];
  __syncthreads();
  const int estart = rs_s[0], eend = rs_s[BN];

  const int pw = lane / NIW;
  const int iw = lane - pw*NIW;

  float acc[G][PP][TI];
  #pragma unroll
  for(int g=0;g<G;g++)
    #pragma unroll
    for(int p=0;p<PP;p++)
      #pragma unroll
      for(int u=0;u<TI;u++) acc[g][p][u]=0.f;

  const float4* H4 = (const float4*)H;
  const float4* x4 = (const float4*)x_in;

  for(int bstart=estart; bstart<eend; bstart+=EB){
    const int ebc = min(EB, eend-bstart);
    if(tid<=BN){ int v = rs_s[tid]-bstart; ro[tid] = min(max(v,0), ebc); }
    for(int j=tid; j<ebc*HV4; j+=256){
      int e = j/HV4, q = j-e*HV4;
      ((float4*)hb)[j] = H4[(size_t)(bstart+e)*32 + p04 + q];
    }
    for(int j=tid; j<ebc*XV; j+=256){
      int e = j/XV, q = j-e*XV;
      int sn = es_src[bstart+e];
      ((float4*)xs)[j] = x4[(size_t)sn*XV + q];
    }
    __syncthreads();
    // wave-private scatter: only the owning wave touches its nodes' edges
    #pragma unroll
    for(int g=0; g<G; g++){
      const int nl = wid*G + g;
      const int a = ro[nl], b = ro[nl+1];
      for(int e=a; e<b; e++){
        float hv[PP];
        #pragma unroll
        for(int p=0;p<PP;p++) hv[p] = hb[e*PLEN + pw*PP + p];
        float xv[TI];
        #pragma unroll
        for(int u=0;u<TI;u++) xv[u] = xs[e*IC + iw*TI + u];
        #pragma unroll
        for(int p=0;p<PP;p++)
          #pragma unroll
          for(int u=0;u<TI;u++) acc[g][p][u] += hv[p]*xv[u];
      }
    }
    __syncthreads();
  }

  // dump scaled S (staging area dead)
  #pragma unroll
  for(int g=0; g<G; g++){
    const int nl = wid*G + g;
    const float dv = 1.f/fmaxf((float)(rs_s[nl+1]-rs_s[nl]), 1.f);
    #pragma unroll
    for(int p=0;p<PP;p++)
      #pragma unroll
      for(int u=0;u<TI;u++)
        S[(nl*PLEN + pw*PP + p)*IC + iw*TI + u] = acc[g][p][u]*dv;
  }
  __syncthreads();

  // ---- GEMM: part[split][n][o] = sum_k S[n][k] * W2[split*K + k][o] ----
  const int kq = tid % KQ, oq = tid / KQ;
  const int o0 = oq*TO;
  const float* W2b = W2 + (size_t)split*K*OC + o0;
  float outp[BN][TO];
  #pragma unroll
  for(int n=0;n<BN;n++)
    #pragma unroll
    for(int t=0;t<TO;t++) outp[n][t]=0.f;

  for(int j=0;j<J;j++){
    const int k4 = j*KQ + kq;
    float wv[4][TO];
    #pragma unroll
    for(int r=0;r<4;r++){
      const float* wr = W2b + (size_t)(4*k4+r)*OC;
      if constexpr (TO==4){
        float4 a=*(const float4*)wr;
        wv[r][0]=a.x; wv[r][1]=a.y; wv[r][2]=a.z; wv[r][3]=a.w;
      } else if constexpr (TO==3){
        wv[r][0]=wr[0]; wv[r][1]=wr[1]; wv[r][2]=wr[2];
      } else {
        float2 a=*(const float2*)wr;
        wv[r][0]=a.x; wv[r][1]=a.y;
      }
    }
    #pragma unroll
    for(int n=0;n<BN;n++){
      float4 sv = *(const float4*)&S[n*K + 4*k4];
      #pragma unroll
      for(int t=0;t<TO;t++)
        outp[n][t] += sv.x*wv[0][t] + sv.y*wv[1][t] + sv.z*wv[2][t] + sv.w*wv[3][t];
    }
  }

  if constexpr (RS){
    // butterfly reduce-scatter over the KQ lanes: lane kq ends with flat item kq
    float* af = &outp[0][0];           // BN*TO == KQ flat items
    #pragma unroll
    for(int half=KQ>>1; half>=1; half>>=1){
      #pragma unroll
      for(int j=0;j<half;j++){
        float lo = af[j], hi = af[j+half];
        float send = (kq&half) ? lo : hi;
        float recv = __shfl_xor(send, half, 64);
        af[j] = (kq&half) ? (hi+recv) : (lo+recv);
      }
    }
    const int n = kq/TO, t = kq - n*TO;
    part[((size_t)split*NN + n0+n)*OC + o0 + t] = af[0];
  } else {
    #pragma unroll
    for(int m=KQ>>1; m>=1; m>>=1)
      #pragma unroll
      for(int n=0;n<BN;n++)
        #pragma unroll
        for(int t=0;t<TO;t++) outp[n][t] += __shfl_xor(outp[n][t], m, 64);
    if(kq==0){
      #pragma unroll
      for(int n=0;n<BN;n++){
        float* dst = part + ((size_t)split*NN + n0+n)*OC + o0;
        #pragma unroll
        for(int t=0;t<TO;t++) dst[t] = outp[n][t];
      }
    }
  }
}

// ---------------- epilogue: y = relu(sum_s part[s] + x@root + xbar@b2 + bias) ----------------
template<int IC, int OC, int KS>
__global__ void k_epi(const float* __restrict__ part, const float* __restrict__ x,
                      const float* __restrict__ xbar,
                      const float* __restrict__ root, const float* __restrict__ b2,
                      const float* __restrict__ bias, float* __restrict__ y)
{
  int idx = blockIdx.x*256 + threadIdx.x;
  if(idx >= NN*OC) return;
  int n = idx/OC, o = idx - n*OC;
  float v = bias[o];
  #pragma unroll
  for(int s=0;s<KS;s++) v += part[(size_t)s*NN*OC + idx];
  #pragma unroll
  for(int i=0;i<IC;i++) v += x[(size_t)n*IC+i]*root[i*OC+o];
  #pragma unroll
  for(int i=0;i<IC;i++) v += xbar[(size_t)n*IC+i]*b2[i*OC+o];
  y[idx] = fmaxf(v, 0.f);
}

// ---------------- set2set (2 steps) + final MLP, one wave per graph ----------------
__global__ void k_s2s(const float* __restrict__ xg, const int* __restrict__ batch,
  const float* __restrict__ Wih, const float* __restrict__ Whh,
  const float* __restrict__ bih, const float* __restrict__ bhh,
  const float* __restrict__ l1W, const float* __restrict__ l1b,
  const float* __restrict__ l2W, const float* __restrict__ l2b,
  const float* __restrict__ lfW, const float* __restrict__ lfb,
  float* __restrict__ out)
{
  int g = blockIdx.x, lane = threadIdx.x;
  __shared__ float hs[16], cs[16], qs[32], gs[64], rs[16];
  int r0 = lowerb(batch, NN, g);
  int r1 = lowerb(batch, NN, g+1);
  if(lane<16){ hs[lane]=0.f; cs[lane]=0.f; }
  if(lane<32) qs[lane]=0.f;
  __syncthreads();
  for(int step=0; step<2; step++){
    float gate = bih[lane] + bhh[lane];
    for(int k=0;k<32;k++) gate += qs[k]*Wih[lane*32+k];
    for(int k=0;k<16;k++) gate += hs[k]*Whh[lane*16+k];
    gs[lane] = gate;
    __syncthreads();
    if(lane<16){
      float ig = 1.f/(1.f+expf(-gs[lane]));
      float fg = 1.f/(1.f+expf(-gs[lane+16]));
      float gg = tanhf(gs[lane+32]);
      float og = 1.f/(1.f+expf(-gs[lane+48]));
      float cn = fg*cs[lane] + ig*gg;
      cs[lane] = cn;
      hs[lane] = og*tanhf(cn);
    }
    __syncthreads();
    float m = -1e30f;
    for(int n=r0+lane; n<r1; n+=64){
      float e=0.f;
      for(int k=0;k<16;k++) e += xg[n*16+k]*hs[k];
      m = fmaxf(m, e);
    }
    for(int d=1; d<64; d<<=1) m = fmaxf(m, __shfl_xor(m, d));
    float ssum = 0.f;
    float racc[16];
    #pragma unroll
    for(int k=0;k<16;k++) racc[k]=0.f;
    for(int n=r0+lane; n<r1; n+=64){
      float e=0.f, xv[16];
      #pragma unroll
      for(int k=0;k<16;k++){ xv[k]=xg[n*16+k]; e += xv[k]*hs[k]; }
      float a = expf(e - m);
      ssum += a;
      #pragma unroll
      for(int k=0;k<16;k++) racc[k] += a*xv[k];
    }
    for(int d=1; d<64; d<<=1) ssum += __shfl_xor(ssum, d);
    #pragma unroll
    for(int k=0;k<16;k++)
      for(int d=1; d<64; d<<=1) racc[k] += __shfl_xor(racc[k], d);
    ssum = fmaxf(ssum, 1e-16f);
    if(lane==0){
      #pragma unroll
      for(int k=0;k<16;k++) rs[k] = racc[k]/ssum;
    }
    __syncthreads();
    if(lane<16){ qs[lane]=hs[lane]; qs[16+lane]=rs[lane]; }
    __syncthreads();
  }
  if(lane<16){
    float v = l1b[lane];
    for(int k=0;k<32;k++) v += qs[k]*l1W[k*16+lane];
    gs[lane] = fmaxf(v,0.f);
  }
  __syncthreads();
  if(lane<8){
    float v = l2b[lane];
    for(int k=0;k<16;k++) v += gs[k]*l2W[k*8+lane];
    gs[32+lane] = fmaxf(v,0.f);
  }
  __syncthreads();
  if(lane==0){
    float v = lfb[0];
    for(int k=0;k<8;k++) v += gs[32+k]*lfW[k];
    out[g] = v;
  }
}

extern "C" void kernel_launch(void* const* d_in, const int* in_sizes, int n_in,
                              void* d_out, int out_size, void* d_ws, size_t ws_size,
                              hipStream_t stream) {
  const float* x0   = (const float*)d_in[0];
  const int*   ei   = (const int*)d_in[1];
  const float* ea   = (const float*)d_in[2];
  const int*   batch= (const int*)d_in[3];
  const float* c1W1 = (const float*)d_in[4];  const float* c1b1 = (const float*)d_in[5];
  const float* c1W2 = (const float*)d_in[6];  const float* c1b2 = (const float*)d_in[7];
  const float* c1rt = (const float*)d_in[8];  const float* c1bs = (const float*)d_in[9];
  const float* c2W1 = (const float*)d_in[10]; const float* c2b1 = (const float*)d_in[11];
  const float* c2W2 = (const float*)d_in[12]; const float* c2b2 = (const float*)d_in[13];
  const float* c2rt = (const float*)d_in[14]; const float* c2bs = (const float*)d_in[15];
  const float* c3W1 = (const float*)d_in[16]; const float* c3b1 = (const float*)d_in[17];
  const float* c3W2 = (const float*)d_in[18]; const float* c3b2 = (const float*)d_in[19];
  const float* c3rt = (const float*)d_in[20]; const float* c3bs = (const float*)d_in[21];
  const float* Wih  = (const float*)d_in[22]; const float* Whh  = (const float*)d_in[23];
  const float* bih  = (const float*)d_in[24]; const float* bhh  = (const float*)d_in[25];
  const float* l1W  = (const float*)d_in[26]; const float* l1b  = (const float*)d_in[27];
  const float* l2W  = (const float*)d_in[28]; const float* l2b  = (const float*)d_in[29];
  const float* lfW  = (const float*)d_in[30]; const float* lfb  = (const float*)d_in[31];
  float* out = (float*)d_out;

  const int* src = ei;
  const int* tgt = ei + NE;

  // workspace carve (~140 MB)
  char* w = (char*)d_ws;
  auto carve = [&](size_t bytes)->void*{ void* p = (void*)w; w += (bytes + 255) & ~(size_t)255; return p; };
  int*   row_start = (int*)carve((NN+1)*sizeof(int));
  int*   cur       = (int*)carve(NN*sizeof(int));
  int*   es_src    = (int*)carve(NE*sizeof(int));
  float* es_ea     = (float*)carve((size_t)NE*16*sizeof(float));
  float* Hbuf      = (float*)carve((size_t)NE*128*sizeof(float));
  float* xbar      = (float*)carve((size_t)NN*48*sizeof(float));
  float* y1   = (float*)carve((size_t)NN*48*sizeof(float));
  float* y2   = (float*)carve((size_t)NN*32*sizeof(float));
  float* y3   = (float*)carve((size_t)NN*16*sizeof(float));
  float* part = (float*)carve((size_t)4*NN*48*sizeof(float));

  // ---- CSR by tgt (+ fused ea gather)
  hipMemsetAsync(cur, 0, NN*sizeof(int), stream);
  k_count<<<(NE+255)/256, 256, 0, stream>>>(tgt, cur);
  k_scan<<<1, 1024, 0, stream>>>(cur, row_start);
  hipMemsetAsync(cur, 0, NN*sizeof(int), stream);
  k_place<<<(NE+255)/256, 256, 0, stream>>>(src, tgt, ea, row_start, cur, es_src, es_ea);

  // ---- layer 1: IC=16 OC=48 | PLEN=64 KS=2 BN=8 G=2 PP=4 TI=4 | KQ=16 TO=3 tree
  k_hmlp<<<NE/8, 256, 0, stream>>>(es_ea, c1W1, c1b1, Hbuf);
  k_xbar<16><<<NN/4, 256, 0, stream>>>(x0, es_src, row_start, xbar);
  k_layer<16,48,64,2,8,4,4,16,3,false><<<(NN/8)*2, 256, 0, stream>>>(x0, Hbuf, es_src, row_start, c1W2, part);
  k_epi<16,48,2><<<(NN*48+255)/256, 256, 0, stream>>>(part, x0, xbar, c1rt, c1b2, c1bs, y1);

  // ---- layer 2: IC=48 OC=32 | PLEN=32 KS=4 BN=8 G=2 PP=4 TI=6 | KQ=32 TO=4 reduce-scatter
  k_hmlp<<<NE/8, 256, 0, stream>>>(es_ea, c2W1, c2b1, Hbuf);
  k_xbar<48><<<NN/4, 256, 0, stream>>>(y1, es_src, row_start, xbar);
  k_layer<48,32,32,4,8,4,6,32,4,true><<<(NN/8)*4, 256, 0, stream>>>(y1, Hbuf, es_src, row_start, c2W2, part);
  k_epi<48,32,4><<<(NN*32+255)/256, 256, 0, stream>>>(part, y1, xbar, c2rt, c2b2, c2bs, y2);

  // ---- layer 3: IC=32 OC=16 | PLEN=64 KS=2 BN=4 G=1 PP=4 TI=8 | KQ=32 TO=2 tree
  k_hmlp<<<NE/8, 256, 0, stream>>>(es_ea, c3W1, c3b1, Hbuf);
  k_xbar<32><<<NN/4, 256, 0, stream>>>(y2, es_src, row_start, xbar);
  k_layer<32,16,64,2,4,4,8,32,2,false><<<(NN/4)*2, 256, 0, stream>>>(y2, Hbuf, es_src, row_start, c3W2, part);
  k_epi<32,16,2><<<(NN*16+255)/256, 256, 0, stream>>>(part, y2, xbar, c3rt, c3b2, c3bs, y3);

  // ---- set2set + MLP head
  k_s2s<<<NG, 64, 0, stream>>>(y3, batch, Wih, Whh, bih, bhh, l1W, l1b, l2W, l2b, lfW, lfb, out);
}

// Round 11
// 944.250 us; speedup vs baseline: 1.4636x; 1.2716x over previous
//
#include <hip/hip_runtime.h>

#define NN 20000
#define NE 200000
#define NG 512

constexpr int EB = 64;   // edges staged per batch

__device__ __forceinline__ int lowerb(const int* a, int n, int v){
  int lo=0, hi=n;
  while(lo<hi){ int m=(lo+hi)>>1; if(a[m]<v) lo=m+1; else hi=m; }
  return lo;
}

// ---------------- counting sort by tgt -> CSR ----------------
__global__ void k_count(const int* __restrict__ tgt, int* __restrict__ cnt){
  int e = blockIdx.x*blockDim.x + threadIdx.x;
  if(e<NE) atomicAdd(&cnt[tgt[e]], 1);
}

__global__ void k_scan(const int* __restrict__ cnt, int* __restrict__ row_start){
  __shared__ int part[1024];
  int t = threadIdx.x;
  const int CH = (NN + 1023)/1024; // 20
  int i0 = t*CH;
  int s = 0;
  for(int j=0;j<CH;j++){ int i=i0+j; if(i<NN) s += cnt[i]; }
  part[t] = s; __syncthreads();
  for(int d=1; d<1024; d<<=1){
    int v = (t>=d) ? part[t-d] : 0;
    __syncthreads();
    part[t] += v;
    __syncthreads();
  }
  int run = (t==0) ? 0 : part[t-1];
  for(int j=0;j<CH;j++){ int i=i0+j; if(i<NN){ row_start[i]=run; run += cnt[i]; } }
  if(t==0) row_start[NN] = part[1023];
}

// place edges in CSR order AND gather edge_attr to CSR order (fused)
__global__ void k_place(const int* __restrict__ src, const int* __restrict__ tgt,
                        const float* __restrict__ ea,
                        const int* __restrict__ row_start, int* __restrict__ cur,
                        int* __restrict__ es_src, float* __restrict__ es_ea){
  int e = blockIdx.x*blockDim.x + threadIdx.x;
  if(e>=NE) return;
  int n = tgt[e];
  int pos = row_start[n] + atomicAdd(&cur[n],1);
  es_src[pos] = src[e];
  const float4* s = (const float4*)ea + (size_t)e*4;
  float4* d = (float4*)es_ea + (size_t)pos*4;
  d[0]=s[0]; d[1]=s[1]; d[2]=s[2]; d[3]=s[3];
}

// ---------------- H = relu(es_ea @ W1 + b1), CSR-ordered, E x 128 ----------------
__launch_bounds__(256, 4)
__global__ void k_hmlp(const float* __restrict__ es_ea, const float* __restrict__ W1,
                       const float* __restrict__ b1, float* __restrict__ H){
  const int pc = threadIdx.x & 31, er = threadIdx.x >> 5;
  const size_t e = (size_t)blockIdx.x*8 + er;
  float4 w1v[16];
  #pragma unroll
  for(int i=0;i<16;i++) w1v[i] = *(const float4*)&W1[i*128 + pc*4];
  float4 hv = *(const float4*)&b1[pc*4];
  float eav[16];
  const float4* eap = (const float4*)(es_ea + e*16);
  #pragma unroll
  for(int q=0;q<4;q++){
    float4 v = eap[q];
    eav[q*4+0]=v.x; eav[q*4+1]=v.y; eav[q*4+2]=v.z; eav[q*4+3]=v.w;
  }
  #pragma unroll
  for(int i=0;i<16;i++){
    hv.x += eav[i]*w1v[i].x;
    hv.y += eav[i]*w1v[i].y;
    hv.z += eav[i]*w1v[i].z;
    hv.w += eav[i]*w1v[i].w;
  }
  hv.x = fmaxf(hv.x,0.f); hv.y = fmaxf(hv.y,0.f);
  hv.z = fmaxf(hv.z,0.f); hv.w = fmaxf(hv.w,0.f);
  *(float4*)&H[e*128 + pc*4] = hv;
}

// ---------------- xbar[n,i] = mean over in-edges of x[src,i] ----------------
template<int IC>
__global__ void k_xbar(const float* __restrict__ x, const int* __restrict__ es_src,
                       const int* __restrict__ row_start, float* __restrict__ xbar){
  constexpr int TI = IC/16;
  const int wid = threadIdx.x>>6, lane = threadIdx.x&63;
  const int n = blockIdx.x*4 + wid;
  const int eg = lane>>4, ig = lane&15;
  const int a = row_start[n], b = row_start[n+1];
  float s[TI];
  #pragma unroll
  for(int u=0;u<TI;u++) s[u]=0.f;
  for(int e=a+eg; e<b; e+=4){
    int sn = es_src[e];
    #pragma unroll
    for(int u=0;u<TI;u++) s[u] += x[(size_t)sn*IC + ig*TI + u];
  }
  #pragma unroll
  for(int u=0;u<TI;u++){
    s[u] += __shfl_xor(s[u], 16, 64);
    s[u] += __shfl_xor(s[u], 32, 64);
  }
  if(eg==0){
    float dinv = 1.f/fmaxf((float)(b-a), 1.f);
    #pragma unroll
    for(int u=0;u<TI;u++) xbar[(size_t)n*IC + ig*TI + u] = s[u]*dinv;
  }
}

// ---------------- fused NNConv layer: wave-private scatter + coalesced k-split GEMM ----------------
// Scatter: wave w owns G=BN/4 nodes; lane=(pw,iw); acc[G][PP][TI] <= 48 floats.
// PF: software-pipeline edge loop (prefetch e+1 h/x regs) where register budget allows.
// GEMM: lane=(kql=lane/OQ, oq=lane%OQ); k-range split across 4 waves x KQL lanes.
// W2 loads coalesced across oq lanes (contiguous row segment). Intra-wave shuffle
// reduce over kql; wave stores its partial to slice (split*4+wid); epi sums slices.
template<int IC, int OC, int PLEN, int KS, int BN, int PP, int TI, int OQ, int TO, bool PF>
__launch_bounds__(256, 3)
__global__ void k_layer(const float* __restrict__ x_in, const float* __restrict__ H,
                        const int* __restrict__ es_src, const int* __restrict__ row_start,
                        const float* __restrict__ W2, float* __restrict__ part)
{
  constexpr int K    = PLEN*IC;
  constexpr int HV4  = PLEN/4;
  constexpr int XV   = IC/4;
  constexpr int NIW  = IC/TI;
  constexpr int NPW  = PLEN/PP;
  constexpr int G    = BN/4;
  constexpr int KQL  = 64/OQ;
  constexpr int TSPL = 4*KQL;
  constexpr int J    = (K/4)/TSPL;
  static_assert(NPW*NIW==64, "wave tile covers 64 lanes");
  static_assert(G*PP*TI <= 48, "spill-safe accumulator");
  static_assert(EB*(PLEN+IC) <= BN*K, "staging alias fits in S");
  static_assert(OQ*TO==OC && (K/4)%TSPL==0, "gemm tiling");

  __shared__ __align__(16) float S[BN*K];
  __shared__ int rs_s[BN+1], ro[BN+1];

  float* hb = S;                 // EB*PLEN staged H slice
  float* xs = S + EB*PLEN;       // EB*IC staged x[src]

  const int tid = threadIdx.x;
  const int wid = tid>>6, lane = tid&63;
  const int split = blockIdx.x % KS;
  const int nb = blockIdx.x / KS;
  const int n0 = nb*BN;
  const int p04 = split*HV4;

  if(tid<=BN) rs_s[tid] = row_start[n0+tid];
  __syncthreads();
  const int estart = rs_s[0], eend = rs_s[BN];

  const int pw = lane / NIW;
  const int iw = lane - pw*NIW;

  float acc[G][PP][TI];
  #pragma unroll
  for(int g=0;g<G;g++)
    #pragma unroll
    for(int p=0;p<PP;p++)
      #pragma unroll
      for(int u=0;u<TI;u++) acc[g][p][u]=0.f;

  const float4* H4 = (const float4*)H;
  const float4* x4 = (const float4*)x_in;

  for(int bstart=estart; bstart<eend; bstart+=EB){
    const int ebc = min(EB, eend-bstart);
    if(tid<=BN){ int v = rs_s[tid]-bstart; ro[tid] = min(max(v,0), ebc); }
    for(int j=tid; j<ebc*HV4; j+=256){
      int e = j/HV4, q = j-e*HV4;
      ((float4*)hb)[j] = H4[(size_t)(bstart+e)*32 + p04 + q];
    }
    for(int j=tid; j<ebc*XV; j+=256){
      int e = j/XV, q = j-e*XV;
      int sn = es_src[bstart+e];
      ((float4*)xs)[j] = x4[(size_t)sn*XV + q];
    }
    __syncthreads();
    // wave-private scatter (only the owning wave touches its nodes' edges)
    if constexpr (PF){
      #pragma unroll
      for(int g=0; g<G; g++){
        const int nl = wid*G + g;
        const int a = ro[nl], b = ro[nl+1];
        if(a>=b) continue;
        float hv[PP], xv[TI];
        #pragma unroll
        for(int p=0;p<PP;p++) hv[p] = hb[a*PLEN + pw*PP + p];
        #pragma unroll
        for(int u=0;u<TI;u++) xv[u] = xs[a*IC + iw*TI + u];
        for(int e=a; e<b; e++){
          float hn[PP], xn[TI];
          if(e+1<b){
            #pragma unroll
            for(int p=0;p<PP;p++) hn[p] = hb[(e+1)*PLEN + pw*PP + p];
            #pragma unroll
            for(int u=0;u<TI;u++) xn[u] = xs[(e+1)*IC + iw*TI + u];
          }
          #pragma unroll
          for(int p=0;p<PP;p++)
            #pragma unroll
            for(int u=0;u<TI;u++) acc[g][p][u] += hv[p]*xv[u];
          #pragma unroll
          for(int p=0;p<PP;p++) hv[p]=hn[p];
          #pragma unroll
          for(int u=0;u<TI;u++) xv[u]=xn[u];
        }
      }
    } else {
      #pragma unroll
      for(int g=0; g<G; g++){
        const int nl = wid*G + g;
        const int a = ro[nl], b = ro[nl+1];
        for(int e=a; e<b; e++){
          float hv[PP];
          #pragma unroll
          for(int p=0;p<PP;p++) hv[p] = hb[e*PLEN + pw*PP + p];
          float xv[TI];
          #pragma unroll
          for(int u=0;u<TI;u++) xv[u] = xs[e*IC + iw*TI + u];
          #pragma unroll
          for(int p=0;p<PP;p++)
            #pragma unroll
            for(int u=0;u<TI;u++) acc[g][p][u] += hv[p]*xv[u];
        }
      }
    }
    __syncthreads();
  }

  // dump scaled S (staging area dead)
  #pragma unroll
  for(int g=0; g<G; g++){
    const int nl = wid*G + g;
    const float dv = 1.f/fmaxf((float)(rs_s[nl+1]-rs_s[nl]), 1.f);
    #pragma unroll
    for(int p=0;p<PP;p++)
      #pragma unroll
      for(int u=0;u<TI;u++)
        S[(nl*PLEN + pw*PP + p)*IC + iw*TI + u] = acc[g][p][u]*dv;
  }
  __syncthreads();

  // ---- GEMM: slice[n][o] partial over this wave's k-range; coalesced W2 ----
  const int oq  = lane % OQ;
  const int kql = lane / OQ;
  const int o0  = oq*TO;
  const float* W2b = W2 + (size_t)split*K*OC + o0;
  float outp[BN][TO];
  #pragma unroll
  for(int n=0;n<BN;n++)
    #pragma unroll
    for(int t=0;t<TO;t++) outp[n][t]=0.f;

  for(int j=0;j<J;j++){
    const int k4 = j*TSPL + wid*KQL + kql;
    float wv[4][TO];
    #pragma unroll
    for(int r=0;r<4;r++){
      const float* wr = W2b + (size_t)(4*k4+r)*OC;
      if constexpr (TO==4){
        float4 a=*(const float4*)wr;
        wv[r][0]=a.x; wv[r][1]=a.y; wv[r][2]=a.z; wv[r][3]=a.w;
      } else if constexpr (TO==3){
        wv[r][0]=wr[0]; wv[r][1]=wr[1]; wv[r][2]=wr[2];
      } else {
        float2 a=*(const float2*)wr;
        wv[r][0]=a.x; wv[r][1]=a.y;
      }
    }
    #pragma unroll
    for(int n=0;n<BN;n++){
      float4 sv = *(const float4*)&S[n*K + 4*k4];
      #pragma unroll
      for(int t=0;t<TO;t++)
        outp[n][t] += sv.x*wv[0][t] + sv.y*wv[1][t] + sv.z*wv[2][t] + sv.w*wv[3][t];
    }
  }
  // intra-wave reduce over kql lanes (masks OQ..32)
  #pragma unroll
  for(int m=OQ; m<64; m<<=1)
    #pragma unroll
    for(int n=0;n<BN;n++)
      #pragma unroll
      for(int t=0;t<TO;t++) outp[n][t] += __shfl_xor(outp[n][t], m, 64);

  if(kql==0){
    float* slice = part + (size_t)(split*4+wid)*NN*OC;
    #pragma unroll
    for(int n=0;n<BN;n++){
      float* dst = slice + (size_t)(n0+n)*OC + o0;
      if constexpr (TO==4){
        *(float4*)dst = make_float4(outp[n][0],outp[n][1],outp[n][2],outp[n][3]);
      } else if constexpr (TO==3){
        dst[0]=outp[n][0]; dst[1]=outp[n][1]; dst[2]=outp[n][2];
      } else {
        *(float2*)dst = make_float2(outp[n][0],outp[n][1]);
      }
    }
  }
}

// ---------------- epilogue: y = relu(sum_s part[s] + x@root + xbar@b2 + bias) ----------------
template<int IC, int OC, int SL>
__global__ void k_epi(const float* __restrict__ part, const float* __restrict__ x,
                      const float* __restrict__ xbar,
                      const float* __restrict__ root, const float* __restrict__ b2,
                      const float* __restrict__ bias, float* __restrict__ y)
{
  int idx = blockIdx.x*256 + threadIdx.x;
  if(idx >= NN*OC) return;
  int n = idx/OC, o = idx - n*OC;
  float v = bias[o];
  #pragma unroll
  for(int s=0;s<SL;s++) v += part[(size_t)s*NN*OC + idx];
  #pragma unroll
  for(int i=0;i<IC;i++) v += x[(size_t)n*IC+i]*root[i*OC+o];
  #pragma unroll
  for(int i=0;i<IC;i++) v += xbar[(size_t)n*IC+i]*b2[i*OC+o];
  y[idx] = fmaxf(v, 0.f);
}

// ---------------- set2set (2 steps) + final MLP, one wave per graph ----------------
__global__ void k_s2s(const float* __restrict__ xg, const int* __restrict__ batch,
  const float* __restrict__ Wih, const float* __restrict__ Whh,
  const float* __restrict__ bih, const float* __restrict__ bhh,
  const float* __restrict__ l1W, const float* __restrict__ l1b,
  const float* __restrict__ l2W, const float* __restrict__ l2b,
  const float* __restrict__ lfW, const float* __restrict__ lfb,
  float* __restrict__ out)
{
  int g = blockIdx.x, lane = threadIdx.x;
  __shared__ float hs[16], cs[16], qs[32], gs[64], rs[16];
  int r0 = lowerb(batch, NN, g);
  int r1 = lowerb(batch, NN, g+1);
  if(lane<16){ hs[lane]=0.f; cs[lane]=0.f; }
  if(lane<32) qs[lane]=0.f;
  __syncthreads();
  for(int step=0; step<2; step++){
    float gate = bih[lane] + bhh[lane];
    for(int k=0;k<32;k++) gate += qs[k]*Wih[lane*32+k];
    for(int k=0;k<16;k++) gate += hs[k]*Whh[lane*16+k];
    gs[lane] = gate;
    __syncthreads();
    if(lane<16){
      float ig = 1.f/(1.f+expf(-gs[lane]));
      float fg = 1.f/(1.f+expf(-gs[lane+16]));
      float gg = tanhf(gs[lane+32]);
      float og = 1.f/(1.f+expf(-gs[lane+48]));
      float cn = fg*cs[lane] + ig*gg;
      cs[lane] = cn;
      hs[lane] = og*tanhf(cn);
    }
    __syncthreads();
    float m = -1e30f;
    for(int n=r0+lane; n<r1; n+=64){
      float e=0.f;
      for(int k=0;k<16;k++) e += xg[n*16+k]*hs[k];
      m = fmaxf(m, e);
    }
    for(int d=1; d<64; d<<=1) m = fmaxf(m, __shfl_xor(m, d));
    float ssum = 0.f;
    float racc[16];
    #pragma unroll
    for(int k=0;k<16;k++) racc[k]=0.f;
    for(int n=r0+lane; n<r1; n+=64){
      float e=0.f, xv[16];
      #pragma unroll
      for(int k=0;k<16;k++){ xv[k]=xg[n*16+k]; e += xv[k]*hs[k]; }
      float a = expf(e - m);
      ssum += a;
      #pragma unroll
      for(int k=0;k<16;k++) racc[k] += a*xv[k];
    }
    for(int d=1; d<64; d<<=1) ssum += __shfl_xor(ssum, d);
    #pragma unroll
    for(int k=0;k<16;k++)
      for(int d=1; d<64; d<<=1) racc[k] += __shfl_xor(racc[k], d);
    ssum = fmaxf(ssum, 1e-16f);
    if(lane==0){
      #pragma unroll
      for(int k=0;k<16;k++) rs[k] = racc[k]/ssum;
    }
    __syncthreads();
    if(lane<16){ qs[lane]=hs[lane]; qs[16+lane]=rs[lane]; }
    __syncthreads();
  }
  if(lane<16){
    float v = l1b[lane];
    for(int k=0;k<32;k++) v += qs[k]*l1W[k*16+lane];
    gs[lane] = fmaxf(v,0.f);
  }
  __syncthreads();
  if(lane<8){
    float v = l2b[lane];
    for(int k=0;k<16;k++) v += gs[k]*l2W[k*8+lane];
    gs[32+lane] = fmaxf(v,0.f);
  }
  __syncthreads();
  if(lane==0){
    float v = lfb[0];
    for(int k=0;k<8;k++) v += gs[32+k]*lfW[k];
    out[g] = v;
  }
}

extern "C" void kernel_launch(void* const* d_in, const int* in_sizes, int n_in,
                              void* d_out, int out_size, void* d_ws, size_t ws_size,
                              hipStream_t stream) {
  const float* x0   = (const float*)d_in[0];
  const int*   ei   = (const int*)d_in[1];
  const float* ea   = (const float*)d_in[2];
  const int*   batch= (const int*)d_in[3];
  const float* c1W1 = (const float*)d_in[4];  const float* c1b1 = (const float*)d_in[5];
  const float* c1W2 = (const float*)d_in[6];  const float* c1b2 = (const float*)d_in[7];
  const float* c1rt = (const float*)d_in[8];  const float* c1bs = (const float*)d_in[9];
  const float* c2W1 = (const float*)d_in[10]; const float* c2b1 = (const float*)d_in[11];
  const float* c2W2 = (const float*)d_in[12]; const float* c2b2 = (const float*)d_in[13];
  const float* c2rt = (const float*)d_in[14]; const float* c2bs = (const float*)d_in[15];
  const float* c3W1 = (const float*)d_in[16]; const float* c3b1 = (const float*)d_in[17];
  const float* c3W2 = (const float*)d_in[18]; const float* c3b2 = (const float*)d_in[19];
  const float* c3rt = (const float*)d_in[20]; const float* c3bs = (const float*)d_in[21];
  const float* Wih  = (const float*)d_in[22]; const float* Whh  = (const float*)d_in[23];
  const float* bih  = (const float*)d_in[24]; const float* bhh  = (const float*)d_in[25];
  const float* l1W  = (const float*)d_in[26]; const float* l1b  = (const float*)d_in[27];
  const float* l2W  = (const float*)d_in[28]; const float* l2b  = (const float*)d_in[29];
  const float* lfW  = (const float*)d_in[30]; const float* lfb  = (const float*)d_in[31];
  float* out = (float*)d_out;

  const int* src = ei;
  const int* tgt = ei + NE;

  // workspace carve (~170 MB)
  char* w = (char*)d_ws;
  auto carve = [&](size_t bytes)->void*{ void* p = (void*)w; w += (bytes + 255) & ~(size_t)255; return p; };
  int*   row_start = (int*)carve((NN+1)*sizeof(int));
  int*   cur       = (int*)carve(NN*sizeof(int));
  int*   es_src    = (int*)carve(NE*sizeof(int));
  float* es_ea     = (float*)carve((size_t)NE*16*sizeof(float));
  float* Hbuf      = (float*)carve((size_t)NE*128*sizeof(float));
  float* xbar      = (float*)carve((size_t)NN*48*sizeof(float));
  float* y1   = (float*)carve((size_t)NN*48*sizeof(float));
  float* y2   = (float*)carve((size_t)NN*32*sizeof(float));
  float* y3   = (float*)carve((size_t)NN*16*sizeof(float));
  float* part = (float*)carve((size_t)16*NN*48*sizeof(float)); // up to 16 slices

  // ---- CSR by tgt (+ fused ea gather)
  hipMemsetAsync(cur, 0, NN*sizeof(int), stream);
  k_count<<<(NE+255)/256, 256, 0, stream>>>(tgt, cur);
  k_scan<<<1, 1024, 0, stream>>>(cur, row_start);
  hipMemsetAsync(cur, 0, NN*sizeof(int), stream);
  k_place<<<(NE+255)/256, 256, 0, stream>>>(src, tgt, ea, row_start, cur, es_src, es_ea);

  // ---- layer 1: IC=16 OC=48 | PLEN=64 KS=2 BN=8 G=2 PP=4 TI=4 | OQ=16 TO=3 | PF on (8 slices)
  k_hmlp<<<NE/8, 256, 0, stream>>>(es_ea, c1W1, c1b1, Hbuf);
  k_xbar<16><<<NN/4, 256, 0, stream>>>(x0, es_src, row_start, xbar);
  k_layer<16,48,64,2,8,4,4,16,3,true><<<(NN/8)*2, 256, 0, stream>>>(x0, Hbuf, es_src, row_start, c1W2, part);
  k_epi<16,48,8><<<(NN*48+255)/256, 256, 0, stream>>>(part, x0, xbar, c1rt, c1b2, c1bs, y1);

  // ---- layer 2: IC=48 OC=32 | PLEN=32 KS=4 BN=8 G=2 PP=4 TI=6 | OQ=8 TO=4 | PF off (16 slices)
  k_hmlp<<<NE/8, 256, 0, stream>>>(es_ea, c2W1, c2b1, Hbuf);
  k_xbar<48><<<NN/4, 256, 0, stream>>>(y1, es_src, row_start, xbar);
  k_layer<48,32,32,4,8,4,6,8,4,false><<<(NN/8)*4, 256, 0, stream>>>(y1, Hbuf, es_src, row_start, c2W2, part);
  k_epi<48,32,16><<<(NN*32+255)/256, 256, 0, stream>>>(part, y1, xbar, c2rt, c2b2, c2bs, y2);

  // ---- layer 3: IC=32 OC=16 | PLEN=64 KS=2 BN=4 G=1 PP=4 TI=8 | OQ=4 TO=4 | PF on (8 slices)
  k_hmlp<<<NE/8, 256, 0, stream>>>(es_ea, c3W1, c3b1, Hbuf);
  k_xbar<32><<<NN/4, 256, 0, stream>>>(y2, es_src, row_start, xbar);
  k_layer<32,16,64,2,4,4,8,4,4,true><<<(NN/4)*2, 256, 0, stream>>>(y2, Hbuf, es_src, row_start, c3W2, part);
  k_epi<32,16,8><<<(NN*16+255)/256, 256, 0, stream>>>(part, y2, xbar, c3rt, c3b2, c3bs, y3);

  // ---- set2set + MLP head
  k_s2s<<<NG, 64, 0, stream>>>(y3, batch, Wih, Whh, bih, bhh, l1W, l1b, l2W, l2b, lfW, lfb, out);
}